// Round 4
// baseline (277.870 us; speedup 1.0000x reference)
//
#include <hip/hip_runtime.h>

#define BATCH 4
#define SEQ   2048
#define EMBED 1024
#define HEADS 16
#define HDIM  64
#define NTOK  (BATCH*SEQ)

typedef __attribute__((ext_vector_type(8)))  short short8;   // 8 bf16 = MFMA A/B frag
typedef __attribute__((ext_vector_type(4)))  float f32x4;    // 16x16 C frag
typedef __attribute__((ext_vector_type(16))) float f32x16;   // 32x32 C frag

static __device__ __forceinline__ unsigned short f2bf(float f) {
    union { float f; unsigned u; } v; v.f = f;
    return (unsigned short)((v.u + 0x7FFFu + ((v.u >> 16) & 1u)) >> 16);  // RNE
}
// pack two floats -> bf16x2: single-instr HW convert (RNE), lo -> low 16
static __device__ __forceinline__ unsigned cvtpk(float lo, float hi) {
    unsigned r;
    asm("v_cvt_pk_bf16_f32 %0, %1, %2" : "=v"(r) : "v"(lo), "v"(hi));
    return r;
}
static __device__ __forceinline__ void gload_lds16(const unsigned short* g, unsigned short* l) {
    __builtin_amdgcn_global_load_lds(
        (__attribute__((address_space(1))) void*)g,
        (__attribute__((address_space(3))) void*)l, 16, 0, 0);
}

#define SCQ 0.180336880f   // log2(e)/8, folded into Q projection

// ---------------------------------------------------------------------------
// All fp32->bf16 casts in one launch: blocks [0,4096) = x, then 4x512 = weights
// ---------------------------------------------------------------------------
__global__ void cast_all(const float* __restrict__ x,
                         const float* __restrict__ w0, const float* __restrict__ w1,
                         const float* __restrict__ w2, const float* __restrict__ w3,
                         unsigned short* __restrict__ xb,
                         unsigned short* __restrict__ wb)
{
    const int bid = blockIdx.x;
    const float* src;
    unsigned short* dst;
    int i;
    if (bid < 4096) {
        src = x; dst = xb; i = (bid * 256 + threadIdx.x) * 8;
    } else {
        const int wz = (bid - 4096) >> 9;
        const float* ws[4] = {w0, w1, w2, w3};
        src = ws[wz];
        dst = wb + (size_t)wz * (EMBED * EMBED);
        i = (((bid - 4096) & 511) * 256 + threadIdx.x) * 8;
    }
    float4 a = *(const float4*)(src + i);
    float4 b = *(const float4*)(src + i + 4);
    union { int4 v; unsigned short u[8]; } pk;
    pk.u[0] = f2bf(a.x); pk.u[1] = f2bf(a.y); pk.u[2] = f2bf(a.z); pk.u[3] = f2bf(a.w);
    pk.u[4] = f2bf(b.x); pk.u[5] = f2bf(b.y); pk.u[6] = f2bf(b.z); pk.u[7] = f2bf(b.w);
    *(int4*)(dst + i) = pk.v;
}

// ---------------------------------------------------------------------------
// Fused QKV GEMM (m97 staging, proven): X staged ONCE per k-step, 3 weight
// tiles staged alongside -> 48 MFMA per 8 gloads. Outputs:
//   z0: Q row-major, pre-scaled by SCQ.  z1: K row-major.
//   z2: V transposed into VtG[bh][d][s] (no masking -- mask folded into attn).
// XCD swizzle: linear dispatch id = by*8+bx -> XCD = bx; give each XCD a
// contiguous 1024-token slice (2 MB, L2-resident) across all feature blocks.
// ---------------------------------------------------------------------------
__global__ __launch_bounds__(256, 2)
void gemm_qkv(const unsigned short* __restrict__ Xb,
              const unsigned short* __restrict__ Wall,
              const float* __restrict__ bq, const float* __restrict__ bk,
              const float* __restrict__ bv,
              unsigned short* __restrict__ Qw, unsigned short* __restrict__ Kw,
              unsigned short* __restrict__ VtG)
{
    __shared__ unsigned short Ws[3][128][32];
    __shared__ unsigned short Xs[128][32];

    const int tid  = threadIdx.x;
    const int bx   = blockIdx.x, by = blockIdx.y;
    const int f0   = (by >> 3) * 128;                  // feature block 0..7
    const int t0   = ((bx << 3) | (by & 7)) * 128;     // token block: XCD-local
    const int lane = tid & 63, m = lane & 15, quad = lane >> 4;
    const int wid  = tid >> 6;
    const int wf   = (wid & 1) * 64;
    const int wt   = (wid >> 1) * 64;

    const int r    = tid >> 2, cc = tid & 3, sw = (tid >> 4) & 3;
    const int gcol = (cc ^ sw) << 3;
    const unsigned short* Xp = Xb + (size_t)(t0 + r) * EMBED + gcol;
    const unsigned short* Wp = Wall + (size_t)(f0 + r) * EMBED + gcol;
    unsigned short* XsL = &Xs[0][0] + tid * 8;
    unsigned short* WsL = &Ws[0][0][0] + tid * 8;

    const int qs = (quad ^ ((m >> 2) & 3)) << 3;

    f32x4 aq[4][4] = {}, ak[4][4] = {}, av[4][4] = {};

    for (int k0 = 0; k0 < EMBED; k0 += 32) {
        __syncthreads();
        gload_lds16(Xp + k0,              XsL);
        gload_lds16(Xp + k0 + 64 * EMBED, XsL + 2048);
#pragma unroll
        for (int z = 0; z < 3; ++z) {
            const unsigned short* wz = Wp + (size_t)z * EMBED * EMBED + k0;
            gload_lds16(wz,              WsL + z * 4096);
            gload_lds16(wz + 64 * EMBED, WsL + z * 4096 + 2048);
        }
        __syncthreads();

        short8 bf4[4];
#pragma unroll
        for (int nb = 0; nb < 4; ++nb)
            bf4[nb] = *(const short8*)&Xs[wt + nb * 16 + m][qs];

#pragma unroll
        for (int z = 0; z < 3; ++z) {
            short8 af[4];
#pragma unroll
            for (int mb = 0; mb < 4; ++mb)
                af[mb] = *(const short8*)&Ws[z][wf + mb * 16 + m][qs];
            f32x4 (&acc)[4][4] = (z == 0) ? aq : (z == 1) ? ak : av;
#pragma unroll
            for (int mb = 0; mb < 4; ++mb)
#pragma unroll
                for (int nb = 0; nb < 4; ++nb)
                    acc[mb][nb] = __builtin_amdgcn_mfma_f32_16x16x32_bf16(
                        af[mb], bf4[nb], acc[mb][nb], 0, 0, 0);
        }
    }

    // ---- Q epilogue (scaled by SCQ) ----
#pragma unroll
    for (int mb = 0; mb < 4; ++mb) {
        const int feat = f0 + wf + mb * 16 + quad * 4;
        float4 bv4 = *(const float4*)&bq[feat];
#pragma unroll
        for (int nb = 0; nb < 4; ++nb) {
            const int tok = t0 + wt + nb * 16 + m;
            ushort4 pk;
            pk.x = f2bf((aq[mb][nb][0] + bv4.x) * SCQ);
            pk.y = f2bf((aq[mb][nb][1] + bv4.y) * SCQ);
            pk.z = f2bf((aq[mb][nb][2] + bv4.z) * SCQ);
            pk.w = f2bf((aq[mb][nb][3] + bv4.w) * SCQ);
            *(ushort4*)(Qw + (size_t)tok * EMBED + feat) = pk;
        }
    }
    // ---- K epilogue ----
#pragma unroll
    for (int mb = 0; mb < 4; ++mb) {
        const int feat = f0 + wf + mb * 16 + quad * 4;
        float4 bv4 = *(const float4*)&bk[feat];
#pragma unroll
        for (int nb = 0; nb < 4; ++nb) {
            const int tok = t0 + wt + nb * 16 + m;
            ushort4 pk;
            pk.x = f2bf(ak[mb][nb][0] + bv4.x);
            pk.y = f2bf(ak[mb][nb][1] + bv4.y);
            pk.z = f2bf(ak[mb][nb][2] + bv4.z);
            pk.w = f2bf(ak[mb][nb][3] + bv4.w);
            *(ushort4*)(Kw + (size_t)tok * EMBED + feat) = pk;
        }
    }
    // ---- V epilogue: transposed, unmasked ----
    {
        const int h = (f0 + wf) >> 6;              // feat block is h-aligned (64)
#pragma unroll
        for (int nb = 0; nb < 4; ++nb) {
            const int tok = t0 + wt + nb * 16 + m;
            const int b   = tok >> 11;
            const int s   = tok & (SEQ - 1);
            const size_t base = ((size_t)(b * HEADS + h) * HDIM) * SEQ + s;
#pragma unroll
            for (int mb = 0; mb < 4; ++mb) {
                const int feat  = f0 + wf + mb * 16 + quad * 4;
                const int dbase = mb * 16 + quad * 4;
                float4 bv4 = *(const float4*)&bv[feat];
                VtG[base + (size_t)(dbase + 0) * SEQ] = f2bf(av[mb][nb][0] + bv4.x);
                VtG[base + (size_t)(dbase + 1) * SEQ] = f2bf(av[mb][nb][1] + bv4.y);
                VtG[base + (size_t)(dbase + 2) * SEQ] = f2bf(av[mb][nb][2] + bv4.z);
                VtG[base + (size_t)(dbase + 3) * SEQ] = f2bf(av[mb][nb][3] + bv4.w);
            }
        }
    }
}

// ---------------------------------------------------------------------------
// MFMA flash attention, 32x32x16. Two-barrier single-buffer schedule (proven).
// R4: KVBLK=128 keys/tile -- halves the barrier count (16 iters x 2) and the
// number of exposed load->LDS-write latency events. LDS 35.8KB still fits
// 4 blocks/CU. Mask preloaded ONCE as a 64-bit per-lane bitmask (lane q32
// needs only keys == q32 mod 32) -- no global mask loads in the main loop.
//  - Mask folded into scores (R1): seed MFMA, masked s -= 1024 -> p == 0.
//  - Denominator via ones-A-frag MFMA (R3); inv = 1/o2[0].
//  - cvt_pk_bf16 + permlane32_swap for P fragment build (R3, T12).
// ---------------------------------------------------------------------------
__global__ __launch_bounds__(256, 4)
void attn_mfma(const unsigned short* __restrict__ Qb,
               const unsigned short* __restrict__ Kb,
               const unsigned short* __restrict__ VtG,
               const int* __restrict__ mask,
               unsigned short* __restrict__ Ob)
{
    __shared__ unsigned short Ks[128][72];    // [key][d]   18.4 KB
    __shared__ unsigned short Vs[64][136];    // [d][key]   17.4 KB

    const int tid  = threadIdx.x;
    // XCD-local remap: XCD = blockIdx.x % 8 gets 8 contiguous (b,h) groups
    const int lin  = (blockIdx.x & 7) * 128 + (blockIdx.x >> 3);
    const int qb   = lin & 15;
    const int h    = (lin >> 4) & 15;
    const int b    = lin >> 8;
    const int wid  = tid >> 6, lane = tid & 63;
    const int q32  = lane & 31, hi = lane >> 5;
    const int tb   = b * SEQ;
    const int q    = qb * 128 + wid * 32 + q32;

    // Q B-frags (pre-scaled): k = st*16 + hi*8 + j
    const unsigned short* qrow = Qb + (size_t)(tb + q) * EMBED + h * HDIM;
    short8 qf[4];
#pragma unroll
    for (int st = 0; st < 4; ++st)
        qf[st] = *(const short8*)(qrow + st * 16 + hi * 8);

    // mask bitmask: bit j = mask[j*32 + q32] (this lane only ever tests keys
    // congruent to q32 mod 32). 64 coalesced int loads, once per block.
    const int* mrow = mask + b * SEQ;
    unsigned long long mbits = 0;
#pragma unroll 8
    for (int j = 0; j < 64; ++j)
        mbits |= (unsigned long long)(mrow[j * 32 + q32] != 0 ? 1 : 0) << j;

    // mask B-frag: B[q][k]: nonzero only at k==0 (lanes hi==0, j==0)
    short8 mqf = {0, 0, 0, 0, 0, 0, 0, 0};
    mqf[0] = hi ? (short)0 : (short)0xC480;   // bf16(-1024), exact

    // all-ones A-frag for the denominator MFMA (every C row = sum_k P[k][q])
    short8 onef;
#pragma unroll
    for (int j = 0; j < 8; ++j) onef[j] = (short)0x3F80;

    f32x16 o0, o1, o2, z16;
#pragma unroll
    for (int i = 0; i < 16; ++i) { z16[i] = 0.f; }
    o0 = z16; o1 = z16; o2 = z16;

    // staging (KVBLK=128): K tile 128key x 64d -> thread: row tid>>1,
    // col-half (tid&1)*32. V tile 64d x 128key -> thread: row tid>>2,
    // col-quarter (tid&3)*32. 4 x int4 each.
    const int kr = tid >> 1, kc = (tid & 1) * 32;
    const int vr = tid >> 2, vc = (tid & 3) * 32;
    const unsigned short* kSrc = Kb + (size_t)(tb + kr) * EMBED + h * HDIM + kc;
    const unsigned short* vSrc = VtG + ((size_t)(b * HEADS + h) * HDIM + vr) * SEQ + vc;

    for (int kt = 0; kt < SEQ; kt += 128) {
        // loads for THIS tile at loop top; cross-block TLP hides the latency
        const unsigned short* kp = kSrc + (size_t)kt * EMBED;
        int4 kv0 = *(const int4*)(kp);
        int4 kv1 = *(const int4*)(kp + 8);
        int4 kv2 = *(const int4*)(kp + 16);
        int4 kv3 = *(const int4*)(kp + 24);
        int4 vv0 = *(const int4*)(vSrc + kt);
        int4 vv1 = *(const int4*)(vSrc + kt + 8);
        int4 vv2 = *(const int4*)(vSrc + kt + 16);
        int4 vv3 = *(const int4*)(vSrc + kt + 24);
        __syncthreads();
        *(int4*)&Ks[kr][kc]      = kv0;
        *(int4*)&Ks[kr][kc + 8]  = kv1;
        *(int4*)&Ks[kr][kc + 16] = kv2;
        *(int4*)&Ks[kr][kc + 24] = kv3;
        *(int4*)&Vs[vr][vc]      = vv0;
        *(int4*)&Vs[vr][vc + 8]  = vv1;
        *(int4*)&Vs[vr][vc + 16] = vv2;
        *(int4*)&Vs[vr][vc + 24] = vv3;
        __syncthreads();

        // mask A-frags for the 4 key-subblocks: nonzero only at k==0
        const int jb = kt >> 5;
        short8 mkf[4] = {{0,0,0,0,0,0,0,0},{0,0,0,0,0,0,0,0},
                         {0,0,0,0,0,0,0,0},{0,0,0,0,0,0,0,0}};
#pragma unroll
        for (int kb = 0; kb < 4; ++kb)
            mkf[kb][0] = (hi == 0 && !((mbits >> (jb + kb)) & 1))
                         ? (short)0x3F80 : (short)0;

#pragma unroll
        for (int kb = 0; kb < 4; ++kb) {
            // S' = mask-bias + K·Q^T over 4 d-steps (Q pre-scaled -> exp2 domain)
            f32x16 s = __builtin_amdgcn_mfma_f32_32x32x16_bf16(
                mkf[kb], mqf, z16, 0, 0, 0);
#pragma unroll
            for (int st = 0; st < 4; ++st) {
                short8 kf = *(const short8*)&Ks[kb * 32 + q32][st * 16 + hi * 8];
                s = __builtin_amdgcn_mfma_f32_32x32x16_bf16(kf, qf[st], s, 0, 0, 0);
            }

            // p = exp2(s); masked keys give exactly 0; pack via HW cvt_pk
            float p[16];
#pragma unroll
            for (int i = 0; i < 16; ++i) p[i] = __builtin_amdgcn_exp2f(s[i]);
            unsigned D[8];
#pragma unroll
            for (int j = 0; j < 8; ++j) D[j] = cvtpk(p[2 * j], p[2 * j + 1]);

            // PV over 2 chunks of 16 keys; B-frag via permlane32_swap:
            // swap(D0,D2) -> (fr.x, fr.z); swap(D1,D3) -> (fr.y, fr.w)
#pragma unroll
            for (int cl = 0; cl < 2; ++cl) {
                unsigned x0 = D[4 * cl + 0], x1 = D[4 * cl + 1];
                unsigned x2 = D[4 * cl + 2], x3 = D[4 * cl + 3];
                asm("v_permlane32_swap_b32 %0, %1" : "+v"(x0), "+v"(x2));
                asm("v_permlane32_swap_b32 %0, %1" : "+v"(x1), "+v"(x3));
                union { uint4 u; short8 s8; } fr;
                fr.u.x = x0; fr.u.y = x1; fr.u.z = x2; fr.u.w = x3;

                const int kcol = kb * 32 + cl * 16 + hi * 8;
                short8 vf0 = *(const short8*)&Vs[q32][kcol];
                short8 vf1 = *(const short8*)&Vs[32 + q32][kcol];
                o0 = __builtin_amdgcn_mfma_f32_32x32x16_bf16(vf0, fr.s8, o0, 0, 0, 0);
                o1 = __builtin_amdgcn_mfma_f32_32x32x16_bf16(vf1, fr.s8, o1, 0, 0, 0);
                o2 = __builtin_amdgcn_mfma_f32_32x32x16_bf16(onef, fr.s8, o2, 0, 0, 0);
            }
        }
    }

    // denominator: every o2 row = sum_k p (same value), col = this lane's q
    const float inv = 1.0f / o2[0];
    unsigned short* orow = Ob + (size_t)(tb + q) * EMBED + h * HDIM;
#pragma unroll
    for (int db = 0; db < 2; ++db) {
        const f32x16& oo = db ? o1 : o0;
#pragma unroll
        for (int qg = 0; qg < 4; ++qg) {
            ushort4 pk;
            pk.x = f2bf(oo[qg * 4 + 0] * inv);
            pk.y = f2bf(oo[qg * 4 + 1] * inv);
            pk.z = f2bf(oo[qg * 4 + 2] * inv);
            pk.w = f2bf(oo[qg * 4 + 3] * inv);
            *(ushort4*)(orow + db * 32 + qg * 8 + hi * 4) = pk;
        }
    }
}

// ---------------------------------------------------------------------------
// Output GEMM (m97 staging, proven): fp32 out. Same XCD-local token swizzle.
// ---------------------------------------------------------------------------
__global__ __launch_bounds__(256, 2)
void gemm_o(const unsigned short* __restrict__ W, const unsigned short* __restrict__ X,
            const float* __restrict__ bias, float* __restrict__ Cout)
{
    __shared__ unsigned short Ws[128][32];
    __shared__ unsigned short Xs[128][32];

    const int tid  = threadIdx.x;
    const int bx   = blockIdx.x, by = blockIdx.y;
    const int f0   = (by >> 3) * 128;
    const int t0   = ((bx << 3) | (by & 7)) * 128;
    const int lane = tid & 63, m = lane & 15, quad = lane >> 4;
    const int wid  = tid >> 6;
    const int wf   = (wid & 1) * 64;
    const int wt   = (wid >> 1) * 64;

    const int r    = tid >> 2, cc = tid & 3, sw = (tid >> 4) & 3;
    const int gcol = (cc ^ sw) << 3;
    const unsigned short* Wp = W + (size_t)(f0 + r) * EMBED + gcol;
    const unsigned short* Xp = X + (size_t)(t0 + r) * EMBED + gcol;
    unsigned short* WsL = &Ws[0][0] + tid * 8;
    unsigned short* XsL = &Xs[0][0] + tid * 8;

    const int qs = (quad ^ ((m >> 2) & 3)) << 3;

    f32x4 acc[4][4] = {};

    for (int k0 = 0; k0 < EMBED; k0 += 32) {
        __syncthreads();
        gload_lds16(Wp + k0,              WsL);
        gload_lds16(Wp + k0 + 64 * EMBED, WsL + 2048);
        gload_lds16(Xp + k0,              XsL);
        gload_lds16(Xp + k0 + 64 * EMBED, XsL + 2048);
        __syncthreads();

        short8 af[4], bf4[4];
#pragma unroll
        for (int mb = 0; mb < 4; ++mb)
            af[mb] = *(const short8*)&Ws[wf + mb * 16 + m][qs];
#pragma unroll
        for (int nb = 0; nb < 4; ++nb)
            bf4[nb] = *(const short8*)&Xs[wt + nb * 16 + m][qs];
#pragma unroll
        for (int mb = 0; mb < 4; ++mb)
#pragma unroll
            for (int nb = 0; nb < 4; ++nb)
                acc[mb][nb] = __builtin_amdgcn_mfma_f32_16x16x32_bf16(
                    af[mb], bf4[nb], acc[mb][nb], 0, 0, 0);
    }

#pragma unroll
    for (int mb = 0; mb < 4; ++mb) {
        const int feat = f0 + wf + mb * 16 + quad * 4;
        float4 bv4 = *(const float4*)&bias[feat];
#pragma unroll
        for (int nb = 0; nb < 4; ++nb) {
            const int tok = t0 + wt + nb * 16 + m;
            float4 st;
            st.x = acc[mb][nb][0] + bv4.x;
            st.y = acc[mb][nb][1] + bv4.y;
            st.z = acc[mb][nb][2] + bv4.z;
            st.w = acc[mb][nb][3] + bv4.w;
            *(float4*)(Cout + (size_t)tok * EMBED + feat) = st;
        }
    }
}

// ---------------------------------------------------------------------------
extern "C" void kernel_launch(void* const* d_in, const int* in_sizes, int n_in,
                              void* d_out, int out_size, void* d_ws, size_t ws_size,
                              hipStream_t stream)
{
    const float* x    = (const float*)d_in[0];
    const int*   mask = (const int*)  d_in[1];
    const float* Wq   = (const float*)d_in[2];
    const float* bq   = (const float*)d_in[3];
    const float* Wk   = (const float*)d_in[4];
    const float* bk   = (const float*)d_in[5];
    const float* Wv   = (const float*)d_in[6];
    const float* bv   = (const float*)d_in[7];
    const float* Wo   = (const float*)d_in[8];
    const float* bo   = (const float*)d_in[9];
    float* out = (float*)d_out;

    const size_t NE = (size_t)NTOK * EMBED;
    const size_t WE = (size_t)EMBED * EMBED;
    unsigned short* Xb  = (unsigned short*)d_ws;
    unsigned short* Wqb = Xb + NE;            // Wq,Wk,Wv,Wo contiguous
    unsigned short* Wob = Wqb + 3 * WE;
    unsigned short* Qw  = Wob + WE;
    unsigned short* Kw  = Qw + NE;
    unsigned short* VtG = Kw + NE;            // [b*H+h][d][s], d = 0..63
    unsigned short* Ow  = Xb;                 // reuse: Xb dead after projections

    cast_all<<<4096 + 2048, 256, 0, stream>>>(x, Wq, Wk, Wv, Wo, Xb, Wqb);

    gemm_qkv<<<dim3(8, 64), 256, 0, stream>>>(Xb, Wqb, bq, bk, bv, Qw, Kw, VtG);

    attn_mfma<<<BATCH * HEADS * (SEQ / 128), 256, 0, stream>>>(Qw, Kw, VtG, mask, Ow);

    gemm_o<<<dim3(8, 64), 256, 0, stream>>>(Wob, Ow, bo, out);
}

// Round 5
// 271.618 us; speedup vs baseline: 1.0230x; 1.0230x over previous
//
#include <hip/hip_runtime.h>

#define BATCH 4
#define SEQ   2048
#define EMBED 1024
#define HEADS 16
#define HDIM  64
#define NTOK  (BATCH*SEQ)

typedef __attribute__((ext_vector_type(8)))  short short8;   // 8 bf16 = MFMA A/B frag
typedef __attribute__((ext_vector_type(4)))  float f32x4;    // 16x16 C frag
typedef __attribute__((ext_vector_type(16))) float f32x16;   // 32x32 C frag

static __device__ __forceinline__ unsigned short f2bf(float f) {
    union { float f; unsigned u; } v; v.f = f;
    return (unsigned short)((v.u + 0x7FFFu + ((v.u >> 16) & 1u)) >> 16);  // RNE
}
// pack two floats -> bf16x2: single-instr HW convert (RNE), lo -> low 16
static __device__ __forceinline__ unsigned cvtpk(float lo, float hi) {
    unsigned r;
    asm("v_cvt_pk_bf16_f32 %0, %1, %2" : "=v"(r) : "v"(lo), "v"(hi));
    return r;
}
static __device__ __forceinline__ void gload_lds16(const unsigned short* g, unsigned short* l) {
    __builtin_amdgcn_global_load_lds(
        (__attribute__((address_space(1))) void*)g,
        (__attribute__((address_space(3))) void*)l, 16, 0, 0);
}

#define SCQ 0.180336880f   // log2(e)/8, folded into Q projection

// ---------------------------------------------------------------------------
// All fp32->bf16 casts in one launch: blocks [0,4096) = x, then 4x512 = weights
// ---------------------------------------------------------------------------
__global__ void cast_all(const float* __restrict__ x,
                         const float* __restrict__ w0, const float* __restrict__ w1,
                         const float* __restrict__ w2, const float* __restrict__ w3,
                         unsigned short* __restrict__ xb,
                         unsigned short* __restrict__ wb)
{
    const int bid = blockIdx.x;
    const float* src;
    unsigned short* dst;
    int i;
    if (bid < 4096) {
        src = x; dst = xb; i = (bid * 256 + threadIdx.x) * 8;
    } else {
        const int wz = (bid - 4096) >> 9;
        const float* ws[4] = {w0, w1, w2, w3};
        src = ws[wz];
        dst = wb + (size_t)wz * (EMBED * EMBED);
        i = (((bid - 4096) & 511) * 256 + threadIdx.x) * 8;
    }
    float4 a = *(const float4*)(src + i);
    float4 b = *(const float4*)(src + i + 4);
    union { int4 v; unsigned short u[8]; } pk;
    pk.u[0] = f2bf(a.x); pk.u[1] = f2bf(a.y); pk.u[2] = f2bf(a.z); pk.u[3] = f2bf(a.w);
    pk.u[4] = f2bf(b.x); pk.u[5] = f2bf(b.y); pk.u[6] = f2bf(b.z); pk.u[7] = f2bf(b.w);
    *(int4*)(dst + i) = pk.v;
}

// ---------------------------------------------------------------------------
// Fused QKV GEMM (m97 staging, proven): X staged ONCE per k-step, 3 weight
// tiles staged alongside -> 48 MFMA per 8 gloads. Outputs:
//   z0: Q row-major, pre-scaled by SCQ.  z1: K row-major.
//   z2: V transposed into VtG[bh][d][s] (no masking -- mask folded into attn).
// XCD swizzle: linear dispatch id = by*8+bx -> XCD = bx; give each XCD a
// contiguous 1024-token slice (2 MB, L2-resident) across all feature blocks.
// ---------------------------------------------------------------------------
__global__ __launch_bounds__(256, 2)
void gemm_qkv(const unsigned short* __restrict__ Xb,
              const unsigned short* __restrict__ Wall,
              const float* __restrict__ bq, const float* __restrict__ bk,
              const float* __restrict__ bv,
              unsigned short* __restrict__ Qw, unsigned short* __restrict__ Kw,
              unsigned short* __restrict__ VtG)
{
    __shared__ unsigned short Ws[3][128][32];
    __shared__ unsigned short Xs[128][32];

    const int tid  = threadIdx.x;
    const int bx   = blockIdx.x, by = blockIdx.y;
    const int f0   = (by >> 3) * 128;                  // feature block 0..7
    const int t0   = ((bx << 3) | (by & 7)) * 128;     // token block: XCD-local
    const int lane = tid & 63, m = lane & 15, quad = lane >> 4;
    const int wid  = tid >> 6;
    const int wf   = (wid & 1) * 64;
    const int wt   = (wid >> 1) * 64;

    const int r    = tid >> 2, cc = tid & 3, sw = (tid >> 4) & 3;
    const int gcol = (cc ^ sw) << 3;
    const unsigned short* Xp = Xb + (size_t)(t0 + r) * EMBED + gcol;
    const unsigned short* Wp = Wall + (size_t)(f0 + r) * EMBED + gcol;
    unsigned short* XsL = &Xs[0][0] + tid * 8;
    unsigned short* WsL = &Ws[0][0][0] + tid * 8;

    const int qs = (quad ^ ((m >> 2) & 3)) << 3;

    f32x4 aq[4][4] = {}, ak[4][4] = {}, av[4][4] = {};

    for (int k0 = 0; k0 < EMBED; k0 += 32) {
        __syncthreads();
        gload_lds16(Xp + k0,              XsL);
        gload_lds16(Xp + k0 + 64 * EMBED, XsL + 2048);
#pragma unroll
        for (int z = 0; z < 3; ++z) {
            const unsigned short* wz = Wp + (size_t)z * EMBED * EMBED + k0;
            gload_lds16(wz,              WsL + z * 4096);
            gload_lds16(wz + 64 * EMBED, WsL + z * 4096 + 2048);
        }
        __syncthreads();

        short8 bf4[4];
#pragma unroll
        for (int nb = 0; nb < 4; ++nb)
            bf4[nb] = *(const short8*)&Xs[wt + nb * 16 + m][qs];

#pragma unroll
        for (int z = 0; z < 3; ++z) {
            short8 af[4];
#pragma unroll
            for (int mb = 0; mb < 4; ++mb)
                af[mb] = *(const short8*)&Ws[z][wf + mb * 16 + m][qs];
            f32x4 (&acc)[4][4] = (z == 0) ? aq : (z == 1) ? ak : av;
#pragma unroll
            for (int mb = 0; mb < 4; ++mb)
#pragma unroll
                for (int nb = 0; nb < 4; ++nb)
                    acc[mb][nb] = __builtin_amdgcn_mfma_f32_16x16x32_bf16(
                        af[mb], bf4[nb], acc[mb][nb], 0, 0, 0);
        }
    }

    // ---- Q epilogue (scaled by SCQ) ----
#pragma unroll
    for (int mb = 0; mb < 4; ++mb) {
        const int feat = f0 + wf + mb * 16 + quad * 4;
        float4 bv4 = *(const float4*)&bq[feat];
#pragma unroll
        for (int nb = 0; nb < 4; ++nb) {
            const int tok = t0 + wt + nb * 16 + m;
            ushort4 pk;
            pk.x = f2bf((aq[mb][nb][0] + bv4.x) * SCQ);
            pk.y = f2bf((aq[mb][nb][1] + bv4.y) * SCQ);
            pk.z = f2bf((aq[mb][nb][2] + bv4.z) * SCQ);
            pk.w = f2bf((aq[mb][nb][3] + bv4.w) * SCQ);
            *(ushort4*)(Qw + (size_t)tok * EMBED + feat) = pk;
        }
    }
    // ---- K epilogue ----
#pragma unroll
    for (int mb = 0; mb < 4; ++mb) {
        const int feat = f0 + wf + mb * 16 + quad * 4;
        float4 bv4 = *(const float4*)&bk[feat];
#pragma unroll
        for (int nb = 0; nb < 4; ++nb) {
            const int tok = t0 + wt + nb * 16 + m;
            ushort4 pk;
            pk.x = f2bf(ak[mb][nb][0] + bv4.x);
            pk.y = f2bf(ak[mb][nb][1] + bv4.y);
            pk.z = f2bf(ak[mb][nb][2] + bv4.z);
            pk.w = f2bf(ak[mb][nb][3] + bv4.w);
            *(ushort4*)(Kw + (size_t)tok * EMBED + feat) = pk;
        }
    }
    // ---- V epilogue: transposed, unmasked ----
    {
        const int h = (f0 + wf) >> 6;              // feat block is h-aligned (64)
#pragma unroll
        for (int nb = 0; nb < 4; ++nb) {
            const int tok = t0 + wt + nb * 16 + m;
            const int b   = tok >> 11;
            const int s   = tok & (SEQ - 1);
            const size_t base = ((size_t)(b * HEADS + h) * HDIM) * SEQ + s;
#pragma unroll
            for (int mb = 0; mb < 4; ++mb) {
                const int feat  = f0 + wf + mb * 16 + quad * 4;
                const int dbase = mb * 16 + quad * 4;
                float4 bv4 = *(const float4*)&bv[feat];
                VtG[base + (size_t)(dbase + 0) * SEQ] = f2bf(av[mb][nb][0] + bv4.x);
                VtG[base + (size_t)(dbase + 1) * SEQ] = f2bf(av[mb][nb][1] + bv4.y);
                VtG[base + (size_t)(dbase + 2) * SEQ] = f2bf(av[mb][nb][2] + bv4.z);
                VtG[base + (size_t)(dbase + 3) * SEQ] = f2bf(av[mb][nb][3] + bv4.w);
            }
        }
    }
}

// ---------------------------------------------------------------------------
// MFMA flash attention, 32x32x16. Two-barrier single-buffer schedule (proven),
// KVBLK=64 (R4's 128 regressed: V-staging bank conflicts).
// R5: TWO q-tiles per wave (64 q-rows). R3 cycle accounting showed LDS-read
// is the binding pipe (16 waves/CU x 16 ds_read_b128 x 12cyc = 3072 cyc/iter
// vs MFMA 2816): every 32-row wave must ingest the full 16KB K+V tile per
// iter. Sharing each kf/vf read across two q-tiles halves LDS-read per unit
// work; tile1's QK MFMAs overlap tile0's exp/cvt on the VALU. Blocks are
// 128 threads x 2 waves (grid unchanged: 4 blocks/CU, fine barrier groups).
//  - Mask folded into scores (R1): ONE shared seed MFMA per kb (mask bias
//    is q-independent), masked s -= 1024 -> p == 0 exactly.
//  - Denominator via ones-A-frag MFMA (R3); inv = 1/o2[0].
//  - cvt_pk_bf16 + permlane32_swap for P fragment build (R3, T12).
//  - Staging maps bank-conflict-free: sr=tid>>1, sc=(tid&1)*32 ->
//    bank-starts tile {0,4,..,28} exactly (stride 36 words == 4 mod 32).
// ---------------------------------------------------------------------------
__global__ __launch_bounds__(128, 2)
void attn_mfma(const unsigned short* __restrict__ Qb,
               const unsigned short* __restrict__ Kb,
               const unsigned short* __restrict__ VtG,
               const int* __restrict__ mask,
               unsigned short* __restrict__ Ob)
{
    __shared__ unsigned short Ks[64][72];     // [key][d]
    __shared__ unsigned short Vs[64][72];     // [d][key]

    const int tid  = threadIdx.x;
    // XCD-local remap: XCD = blockIdx.x % 8 gets 8 contiguous (b,h) groups
    const int lin  = (blockIdx.x & 7) * 128 + (blockIdx.x >> 3);
    const int qb   = lin & 15;
    const int h    = (lin >> 4) & 15;
    const int b    = lin >> 8;
    const int wid  = tid >> 6, lane = tid & 63;   // wid in {0,1}
    const int q32  = lane & 31, hi = lane >> 5;
    const int tb   = b * SEQ;
    const int q0   = qb * 128 + wid * 64 + q32;   // tile t row = q0 + t*32

    // Q B-frags for both tiles (pre-scaled): k = st*16 + hi*8 + j
    short8 qf[2][4];
#pragma unroll
    for (int t = 0; t < 2; ++t) {
        const unsigned short* qrow = Qb + (size_t)(tb + q0 + t * 32) * EMBED + h * HDIM;
#pragma unroll
        for (int st = 0; st < 4; ++st)
            qf[t][st] = *(const short8*)(qrow + st * 16 + hi * 8);
    }

    // mask B-frag: B[q][k]: nonzero only at k==0 (lanes hi==0, j==0)
    short8 mqf = {0, 0, 0, 0, 0, 0, 0, 0};
    mqf[0] = hi ? (short)0 : (short)0xC480;   // bf16(-1024), exact

    // all-ones A-frag for the denominator MFMA (every C row = sum_k P[k][q])
    short8 onef;
#pragma unroll
    for (int j = 0; j < 8; ++j) onef[j] = (short)0x3F80;

    f32x16 o00, o01, o02, o10, o11, o12, z16;
#pragma unroll
    for (int i = 0; i < 16; ++i) { z16[i] = 0.f; }
    o00 = z16; o01 = z16; o02 = z16;
    o10 = z16; o11 = z16; o12 = z16;

    // staging: 128 threads, 4x int4 each for K and V (conflict-free map)
    const int sr = tid >> 1, sc = (tid & 1) * 32;
    const unsigned short* kSrc = Kb + (size_t)(tb + sr) * EMBED + h * HDIM + sc;
    const unsigned short* vSrc = VtG + ((size_t)(b * HEADS + h) * HDIM + sr) * SEQ + sc;
    const int* mrow = mask + b * SEQ;

    for (int kt = 0; kt < SEQ; kt += 64) {
        // loads for THIS tile at loop top; cross-block TLP hides the latency
        const unsigned short* kp = kSrc + (size_t)kt * EMBED;
        int4 kv0 = *(const int4*)(kp);
        int4 kv1 = *(const int4*)(kp + 8);
        int4 kv2 = *(const int4*)(kp + 16);
        int4 kv3 = *(const int4*)(kp + 24);
        int4 vv0 = *(const int4*)(vSrc + kt);
        int4 vv1 = *(const int4*)(vSrc + kt + 8);
        int4 vv2 = *(const int4*)(vSrc + kt + 16);
        int4 vv3 = *(const int4*)(vSrc + kt + 24);
        const int mva = mrow[kt + q32];
        const int mvb = mrow[kt + 32 + q32];
        __syncthreads();
        *(int4*)&Ks[sr][sc]      = kv0;
        *(int4*)&Ks[sr][sc + 8]  = kv1;
        *(int4*)&Ks[sr][sc + 16] = kv2;
        *(int4*)&Ks[sr][sc + 24] = kv3;
        *(int4*)&Vs[sr][sc]      = vv0;
        *(int4*)&Vs[sr][sc + 8]  = vv1;
        *(int4*)&Vs[sr][sc + 16] = vv2;
        *(int4*)&Vs[sr][sc + 24] = vv3;
        __syncthreads();

        // mask A-frags: A[key][k]: nonzero only at k==0: maskbit = 1.0 if masked
        short8 mkfa = {0, 0, 0, 0, 0, 0, 0, 0};
        short8 mkfb = {0, 0, 0, 0, 0, 0, 0, 0};
        mkfa[0] = (hi == 0 && mva == 0) ? (short)0x3F80 : (short)0;
        mkfb[0] = (hi == 0 && mvb == 0) ? (short)0x3F80 : (short)0;

#pragma unroll
        for (int kb = 0; kb < 2; ++kb) {
            // shared seed: mask bias is q-independent -> one MFMA for both tiles
            f32x16 seed = __builtin_amdgcn_mfma_f32_32x32x16_bf16(
                kb ? mkfb : mkfa, mqf, z16, 0, 0, 0);
            short8 kf[4];
#pragma unroll
            for (int st = 0; st < 4; ++st)
                kf[st] = *(const short8*)&Ks[kb * 32 + q32][st * 16 + hi * 8];

            f32x16 s0 = seed, s1 = seed;
#pragma unroll
            for (int st = 0; st < 4; ++st) {
                s0 = __builtin_amdgcn_mfma_f32_32x32x16_bf16(kf[st], qf[0][st], s0, 0, 0, 0);
                s1 = __builtin_amdgcn_mfma_f32_32x32x16_bf16(kf[st], qf[1][st], s1, 0, 0, 0);
            }

            // p = exp2(s); masked keys give exactly 0; pack via HW cvt_pk
            float p[16];
            unsigned D0[8], D1[8];
#pragma unroll
            for (int i = 0; i < 16; ++i) p[i] = __builtin_amdgcn_exp2f(s0[i]);
#pragma unroll
            for (int j = 0; j < 8; ++j) D0[j] = cvtpk(p[2 * j], p[2 * j + 1]);
#pragma unroll
            for (int i = 0; i < 16; ++i) p[i] = __builtin_amdgcn_exp2f(s1[i]);
#pragma unroll
            for (int j = 0; j < 8; ++j) D1[j] = cvtpk(p[2 * j], p[2 * j + 1]);

            // PV over 2 chunks of 16 keys; vf reads SHARED across both q-tiles
#pragma unroll
            for (int cl = 0; cl < 2; ++cl) {
                unsigned a0 = D0[4 * cl + 0], a1 = D0[4 * cl + 1];
                unsigned a2 = D0[4 * cl + 2], a3 = D0[4 * cl + 3];
                asm("v_permlane32_swap_b32 %0, %1" : "+v"(a0), "+v"(a2));
                asm("v_permlane32_swap_b32 %0, %1" : "+v"(a1), "+v"(a3));
                union { uint4 u; short8 s8; } fr0;
                fr0.u.x = a0; fr0.u.y = a1; fr0.u.z = a2; fr0.u.w = a3;

                unsigned b0 = D1[4 * cl + 0], b1 = D1[4 * cl + 1];
                unsigned b2 = D1[4 * cl + 2], b3 = D1[4 * cl + 3];
                asm("v_permlane32_swap_b32 %0, %1" : "+v"(b0), "+v"(b2));
                asm("v_permlane32_swap_b32 %0, %1" : "+v"(b1), "+v"(b3));
                union { uint4 u; short8 s8; } fr1;
                fr1.u.x = b0; fr1.u.y = b1; fr1.u.z = b2; fr1.u.w = b3;

                const int kcol = kb * 32 + cl * 16 + hi * 8;
                short8 vf0 = *(const short8*)&Vs[q32][kcol];
                short8 vf1 = *(const short8*)&Vs[32 + q32][kcol];
                o00 = __builtin_amdgcn_mfma_f32_32x32x16_bf16(vf0, fr0.s8, o00, 0, 0, 0);
                o01 = __builtin_amdgcn_mfma_f32_32x32x16_bf16(vf1, fr0.s8, o01, 0, 0, 0);
                o02 = __builtin_amdgcn_mfma_f32_32x32x16_bf16(onef, fr0.s8, o02, 0, 0, 0);
                o10 = __builtin_amdgcn_mfma_f32_32x32x16_bf16(vf0, fr1.s8, o10, 0, 0, 0);
                o11 = __builtin_amdgcn_mfma_f32_32x32x16_bf16(vf1, fr1.s8, o11, 0, 0, 0);
                o12 = __builtin_amdgcn_mfma_f32_32x32x16_bf16(onef, fr1.s8, o12, 0, 0, 0);
            }
        }
    }

    // denominator per tile: every o*2 row = sum_k p, col = this lane's q
#pragma unroll
    for (int t = 0; t < 2; ++t) {
        const float inv = 1.0f / (t ? o12[0] : o02[0]);
        unsigned short* orow = Ob + (size_t)(tb + q0 + t * 32) * EMBED + h * HDIM;
#pragma unroll
        for (int db = 0; db < 2; ++db) {
            const f32x16& oo = t ? (db ? o11 : o10) : (db ? o01 : o00);
#pragma unroll
            for (int qg = 0; qg < 4; ++qg) {
                ushort4 pk;
                pk.x = f2bf(oo[qg * 4 + 0] * inv);
                pk.y = f2bf(oo[qg * 4 + 1] * inv);
                pk.z = f2bf(oo[qg * 4 + 2] * inv);
                pk.w = f2bf(oo[qg * 4 + 3] * inv);
                *(ushort4*)(orow + db * 32 + qg * 8 + hi * 4) = pk;
            }
        }
    }
}

// ---------------------------------------------------------------------------
// Output GEMM (m97 staging, proven): fp32 out. Same XCD-local token swizzle.
// ---------------------------------------------------------------------------
__global__ __launch_bounds__(256, 2)
void gemm_o(const unsigned short* __restrict__ W, const unsigned short* __restrict__ X,
            const float* __restrict__ bias, float* __restrict__ Cout)
{
    __shared__ unsigned short Ws[128][32];
    __shared__ unsigned short Xs[128][32];

    const int tid  = threadIdx.x;
    const int bx   = blockIdx.x, by = blockIdx.y;
    const int f0   = (by >> 3) * 128;
    const int t0   = ((bx << 3) | (by & 7)) * 128;
    const int lane = tid & 63, m = lane & 15, quad = lane >> 4;
    const int wid  = tid >> 6;
    const int wf   = (wid & 1) * 64;
    const int wt   = (wid >> 1) * 64;

    const int r    = tid >> 2, cc = tid & 3, sw = (tid >> 4) & 3;
    const int gcol = (cc ^ sw) << 3;
    const unsigned short* Wp = W + (size_t)(f0 + r) * EMBED + gcol;
    const unsigned short* Xp = X + (size_t)(t0 + r) * EMBED + gcol;
    unsigned short* WsL = &Ws[0][0] + tid * 8;
    unsigned short* XsL = &Xs[0][0] + tid * 8;

    const int qs = (quad ^ ((m >> 2) & 3)) << 3;

    f32x4 acc[4][4] = {};

    for (int k0 = 0; k0 < EMBED; k0 += 32) {
        __syncthreads();
        gload_lds16(Wp + k0,              WsL);
        gload_lds16(Wp + k0 + 64 * EMBED, WsL + 2048);
        gload_lds16(Xp + k0,              XsL);
        gload_lds16(Xp + k0 + 64 * EMBED, XsL + 2048);
        __syncthreads();

        short8 af[4], bf4[4];
#pragma unroll
        for (int mb = 0; mb < 4; ++mb)
            af[mb] = *(const short8*)&Ws[wf + mb * 16 + m][qs];
#pragma unroll
        for (int nb = 0; nb < 4; ++nb)
            bf4[nb] = *(const short8*)&Xs[wt + nb * 16 + m][qs];
#pragma unroll
        for (int mb = 0; mb < 4; ++mb)
#pragma unroll
            for (int nb = 0; nb < 4; ++nb)
                acc[mb][nb] = __builtin_amdgcn_mfma_f32_16x16x32_bf16(
                    af[mb], bf4[nb], acc[mb][nb], 0, 0, 0);
    }

#pragma unroll
    for (int mb = 0; mb < 4; ++mb) {
        const int feat = f0 + wf + mb * 16 + quad * 4;
        float4 bv4 = *(const float4*)&bias[feat];
#pragma unroll
        for (int nb = 0; nb < 4; ++nb) {
            const int tok = t0 + wt + nb * 16 + m;
            float4 st;
            st.x = acc[mb][nb][0] + bv4.x;
            st.y = acc[mb][nb][1] + bv4.y;
            st.z = acc[mb][nb][2] + bv4.z;
            st.w = acc[mb][nb][3] + bv4.w;
            *(float4*)(Cout + (size_t)tok * EMBED + feat) = st;
        }
    }
}

// ---------------------------------------------------------------------------
extern "C" void kernel_launch(void* const* d_in, const int* in_sizes, int n_in,
                              void* d_out, int out_size, void* d_ws, size_t ws_size,
                              hipStream_t stream)
{
    const float* x    = (const float*)d_in[0];
    const int*   mask = (const int*)  d_in[1];
    const float* Wq   = (const float*)d_in[2];
    const float* bq   = (const float*)d_in[3];
    const float* Wk   = (const float*)d_in[4];
    const float* bk   = (const float*)d_in[5];
    const float* Wv   = (const float*)d_in[6];
    const float* bv   = (const float*)d_in[7];
    const float* Wo   = (const float*)d_in[8];
    const float* bo   = (const float*)d_in[9];
    float* out = (float*)d_out;

    const size_t NE = (size_t)NTOK * EMBED;
    const size_t WE = (size_t)EMBED * EMBED;
    unsigned short* Xb  = (unsigned short*)d_ws;
    unsigned short* Wqb = Xb + NE;            // Wq,Wk,Wv,Wo contiguous
    unsigned short* Wob = Wqb + 3 * WE;
    unsigned short* Qw  = Wob + WE;
    unsigned short* Kw  = Qw + NE;
    unsigned short* VtG = Kw + NE;            // [b*H+h][d][s], d = 0..63
    unsigned short* Ow  = Xb;                 // reuse: Xb dead after projections

    cast_all<<<4096 + 2048, 256, 0, stream>>>(x, Wq, Wk, Wv, Wo, Xb, Wqb);

    gemm_qkv<<<dim3(8, 64), 256, 0, stream>>>(Xb, Wqb, bq, bk, bv, Qw, Kw, VtG);

    attn_mfma<<<BATCH * HEADS * (SEQ / 128), 128, 0, stream>>>(Qw, Kw, VtG, mask, Ow);

    gemm_o<<<dim3(8, 64), 256, 0, stream>>>(Wob, Ow, bo, out);
}